// Round 1
// baseline (1638.581 us; speedup 1.0000x reference)
//
#include <hip/hip_runtime.h>

typedef __attribute__((ext_vector_type(8))) short short8;
typedef __attribute__((ext_vector_type(4))) float f32x4;
typedef __attribute__((ext_vector_type(4))) float f4v;
typedef unsigned short u16;
typedef unsigned int u32;

#define NPTS 65536
#define CCH 512
#define HCH 2048
#define GDIM 66
#define GDIM2 (66*66)

__device__ __forceinline__ u16 f2bf(float f) {
    u32 u = __builtin_bit_cast(u32, f);
    u32 r = (u + 0x7fffu + ((u >> 16) & 1u)) >> 16;
    return (u16)r;
}

__device__ __forceinline__ void gld16(const void* g, void* l) {
    __builtin_amdgcn_global_load_lds((const __attribute__((address_space(1))) void*)g,
                                     (__attribute__((address_space(3))) void*)l, 16, 0, 0);
}

// ---------------- setup kernels ----------------

__global__ void scatter_kernel(const int* __restrict__ coords, int* __restrict__ grid) {
    int i = blockIdx.x * 256 + threadIdx.x;
    if (i < NPTS) {
        int c0 = coords[3*i], c1 = coords[3*i+1], c2 = coords[3*i+2];
        grid[(c0+1)*GDIM2 + (c1+1)*GDIM + (c2+1)] = i;
    }
}

__global__ void build_nbr(const int* __restrict__ coords, const int* __restrict__ grid,
                          int* __restrict__ nbr) {
    int i = blockIdx.x * 256 + threadIdx.x;
    if (i >= NPTS) return;
    int c0 = coords[3*i], c1 = coords[3*i+1], c2 = coords[3*i+2];
    #pragma unroll
    for (int o = 0; o < 27; ++o) {
        int dx = o / 9, dy = (o / 3) % 3, dz = o % 3;
        int v = grid[(c0+dx)*GDIM2 + (c1+dy)*GDIM + (c2+dz)];
        nbr[o*NPTS + i] = (v < 0) ? NPTS : v;   // invalid -> zero row
    }
}

__global__ void cast_bf16(const float* __restrict__ in, u16* __restrict__ out, int n8) {
    int i = blockIdx.x * 256 + threadIdx.x;
    if (i >= n8) return;
    f4v a = *(const f4v*)(in + (size_t)i*8);
    f4v b = *(const f4v*)(in + (size_t)i*8 + 4);
    short8 o;
    #pragma unroll
    for (int j = 0; j < 4; ++j) { o[j] = (short)f2bf(a[j]); o[j+4] = (short)f2bf(b[j]); }
    *(short8*)(out + (size_t)i*8) = o;
}

// in: f32 [R][Cc] row-major (matrix z), out: bf16 [Cc][R]
__global__ void transpose_cast(const float* __restrict__ in, u16* __restrict__ out,
                               int R, int Cc) {
    __shared__ float tile[32][33];
    size_t moff = (size_t)blockIdx.z * R * Cc;
    in += moff; out += moff;
    int tx = threadIdx.x, ty = threadIdx.y;
    #pragma unroll
    for (int j = 0; j < 4; ++j) {
        int r = blockIdx.y*32 + ty + j*8;
        int c = blockIdx.x*32 + tx;
        tile[ty + j*8][tx] = in[(size_t)r*Cc + c];
    }
    __syncthreads();
    #pragma unroll
    for (int j = 0; j < 4; ++j) {
        int orow = blockIdx.x*32 + ty + j*8;   // input col
        int ocol = blockIdx.y*32 + tx;         // input row
        out[(size_t)orow*R + ocol] = f2bf(tile[tx][ty + j*8]);
    }
}

// ---------------- conv GEMM: h[N][512] = bias + sum_o gather(feats)[*]@W_o ----------------

__global__ __launch_bounds__(256) void conv_gemm(
    const u16* __restrict__ fb,      // (N+1) x 512 bf16, row N zeroed
    const int* __restrict__ nbr,     // 27 x N
    const u16* __restrict__ wcT,     // 27 x 512(cout) x 512(cin)
    const float* __restrict__ convb,
    float* __restrict__ h)
{
    __shared__ __align__(1024) char ldsA[16384];
    __shared__ __align__(1024) char ldsB[16384];
    const int t = threadIdx.x;
    const int w = t >> 6, lane = t & 63;
    const int row0 = blockIdx.y * 128, col0 = blockIdx.x * 128;
    const int wm = w >> 1, wn = w & 1;
    const int ccsrc = (lane & 7) ^ (lane >> 3);
    const int laneRow = lane >> 3;

    f32x4 acc[4][4] = {};

    for (int o = 0; o < 27; ++o) {
        const u16* aptr[4];
        #pragma unroll
        for (int it = 0; it < 4; ++it) {
            int r = w*32 + it*8 + laneRow;
            int idx = nbr[o*NPTS + row0 + r];
            aptr[it] = fb + (size_t)idx*512 + ccsrc*8;
        }
        const u16* bbase = wcT + ((size_t)o << 18);
        #pragma unroll 1
        for (int ks = 0; ks < 8; ++ks) {
            int k0 = ks * 64;
            #pragma unroll
            for (int it = 0; it < 4; ++it) {
                int c = w*256 + it*64 + lane;
                gld16(aptr[it] + k0, ldsA + c*16);
            }
            #pragma unroll
            for (int it = 0; it < 4; ++it) {
                int c = w*256 + it*64 + lane;
                int r = w*32 + it*8 + laneRow;
                gld16(bbase + (size_t)(col0 + r)*512 + k0 + ccsrc*8, ldsB + c*16);
            }
            __syncthreads();
            #pragma unroll
            for (int kk = 0; kk < 2; ++kk) {
                short8 a[4], b[4];
                #pragma unroll
                for (int f = 0; f < 4; ++f) {
                    int rowA = wm*64 + f*16 + (lane & 15);
                    int ch = (kk*4 + (lane >> 4)) ^ (lane & 7);
                    a[f] = *(const short8*)(void*)(ldsA + rowA*128 + ch*16);
                    int rowB = wn*64 + f*16 + (lane & 15);
                    b[f] = *(const short8*)(void*)(ldsB + rowB*128 + ch*16);
                }
                #pragma unroll
                for (int i = 0; i < 4; ++i)
                    #pragma unroll
                    for (int j = 0; j < 4; ++j)
                        acc[i][j] = __builtin_amdgcn_mfma_f32_16x16x32_bf16(a[i], b[j], acc[i][j], 0, 0, 0);
            }
            __syncthreads();
        }
    }

    #pragma unroll
    for (int i = 0; i < 4; ++i) {
        int row = row0 + wm*64 + i*16 + (lane >> 4)*4;
        #pragma unroll
        for (int j = 0; j < 4; ++j) {
            int col = col0 + wn*64 + j*16 + (lane & 15);
            float cb = convb[col];
            #pragma unroll
            for (int q = 0; q < 4; ++q)
                h[(size_t)(row + q)*512 + col] = acc[i][j][q] + cb;
        }
    }
}

// ---------------- LayerNorm: h f32 -> nf bf16 ----------------

__global__ __launch_bounds__(256) void ln_kernel(const float* __restrict__ h,
    const float* __restrict__ g, const float* __restrict__ b, u16* __restrict__ nf)
{
    int w = threadIdx.x >> 6, lane = threadIdx.x & 63;
    int row = blockIdx.x*4 + w;
    const float* hr = h + (size_t)row*512;
    f4v v0 = *(const f4v*)(hr + lane*8);
    f4v v1 = *(const f4v*)(hr + lane*8 + 4);
    float x[8];
    #pragma unroll
    for (int j = 0; j < 4; ++j) { x[j] = v0[j]; x[j+4] = v1[j]; }
    float s = 0.f, ss = 0.f;
    #pragma unroll
    for (int j = 0; j < 8; ++j) { s += x[j]; ss += x[j]*x[j]; }
    #pragma unroll
    for (int m = 1; m < 64; m <<= 1) { s += __shfl_xor(s, m); ss += __shfl_xor(ss, m); }
    float mu = s * (1.f/512.f);
    float var = ss * (1.f/512.f) - mu*mu;
    float inv = rsqrtf(var + 1e-6f);
    short8 o;
    #pragma unroll
    for (int j = 0; j < 8; ++j) {
        int c = lane*8 + j;
        o[j] = (short)f2bf((x[j] - mu) * inv * g[c] + b[c]);
    }
    *(short8*)(nf + (size_t)row*512 + lane*8) = o;
}

// ---------------- plain GEMM (MODE 1: +b1,SiLU->bf16 g1 | MODE 2: +b2+resid/acc->f32 out) ----------------

template<int MODE>
__global__ __launch_bounds__(256) void mlp_gemm(
    const u16* __restrict__ A, int lda,
    const u16* __restrict__ BT, int ldb, int K,
    const float* __restrict__ bias,
    const float* __restrict__ resid,
    float* __restrict__ outf,
    u16* __restrict__ outb,
    int first)
{
    __shared__ __align__(1024) char ldsA[16384];
    __shared__ __align__(1024) char ldsB[16384];
    const int t = threadIdx.x;
    const int w = t >> 6, lane = t & 63;
    const int row0 = blockIdx.y * 128, col0 = blockIdx.x * 128;
    const int wm = w >> 1, wn = w & 1;
    const int ccsrc = (lane & 7) ^ (lane >> 3);
    const int laneRow = lane >> 3;

    f32x4 acc[4][4] = {};

    const u16* aptr[4];
    const u16* bptr[4];
    #pragma unroll
    for (int it = 0; it < 4; ++it) {
        int r = w*32 + it*8 + laneRow;
        aptr[it] = A + (size_t)(row0 + r)*lda + ccsrc*8;
        bptr[it] = BT + (size_t)(col0 + r)*ldb + ccsrc*8;
    }

    #pragma unroll 1
    for (int k0 = 0; k0 < K; k0 += 64) {
        #pragma unroll
        for (int it = 0; it < 4; ++it) {
            int c = w*256 + it*64 + lane;
            gld16(aptr[it] + k0, ldsA + c*16);
        }
        #pragma unroll
        for (int it = 0; it < 4; ++it) {
            int c = w*256 + it*64 + lane;
            gld16(bptr[it] + k0, ldsB + c*16);
        }
        __syncthreads();
        #pragma unroll
        for (int kk = 0; kk < 2; ++kk) {
            short8 a[4], b[4];
            #pragma unroll
            for (int f = 0; f < 4; ++f) {
                int rowA = wm*64 + f*16 + (lane & 15);
                int ch = (kk*4 + (lane >> 4)) ^ (lane & 7);
                a[f] = *(const short8*)(void*)(ldsA + rowA*128 + ch*16);
                int rowB = wn*64 + f*16 + (lane & 15);
                b[f] = *(const short8*)(void*)(ldsB + rowB*128 + ch*16);
            }
            #pragma unroll
            for (int i = 0; i < 4; ++i)
                #pragma unroll
                for (int j = 0; j < 4; ++j)
                    acc[i][j] = __builtin_amdgcn_mfma_f32_16x16x32_bf16(a[i], b[j], acc[i][j], 0, 0, 0);
        }
        __syncthreads();
    }

    #pragma unroll
    for (int i = 0; i < 4; ++i) {
        int row = row0 + wm*64 + i*16 + (lane >> 4)*4;
        #pragma unroll
        for (int j = 0; j < 4; ++j) {
            int col = col0 + wn*64 + j*16 + (lane & 15);
            #pragma unroll
            for (int q = 0; q < 4; ++q) {
                float v = acc[i][j][q];
                if (MODE == 1) {
                    float val = v + bias[col];
                    float sg = 1.f / (1.f + expf(-val));
                    outb[(size_t)(row + q)*1024 + col] = f2bf(val * sg);
                } else {
                    size_t idx = (size_t)(row + q)*512 + col;
                    float o = first ? (v + bias[col] + resid[idx]) : (v + outf[idx]);
                    outf[idx] = o;
                }
            }
        }
    }
}

// ---------------- launch ----------------

extern "C" void kernel_launch(void* const* d_in, const int* in_sizes, int n_in,
                              void* d_out, int out_size, void* d_ws, size_t ws_size,
                              hipStream_t stream) {
    const float* feats  = (const float*)d_in[0];
    const int*   coords = (const int*)d_in[1];
    const float* conv_w = (const float*)d_in[2];
    const float* conv_b = (const float*)d_in[3];
    const float* ln_g   = (const float*)d_in[4];
    const float* ln_b   = (const float*)d_in[5];
    const float* w1     = (const float*)d_in[6];
    const float* b1     = (const float*)d_in[7];
    const float* w2     = (const float*)d_in[8];
    const float* b2     = (const float*)d_in[9];
    float* out = (float*)d_out;
    char* ws = (char*)d_ws;

    size_t off = 0;
    auto take = [&](size_t bytes) -> void* {
        void* p = ws + off;
        off += (bytes + 1023) & ~(size_t)1023;
        return p;
    };
    int* grid_i = (int*)take((size_t)GDIM*GDIM2*4);
    int* nbr    = (int*)take(27ull*NPTS*4);
    u16* wcT    = (u16*)take(27ull*512*512*2);
    u16* w1T    = (u16*)take(2048ull*512*2);
    u16* w2T    = (u16*)take(512ull*2048*2);
    u16* fb     = (u16*)take((NPTS+1ull)*512*2);
    void* hbuf  = take(134217728ull);
    float* h = (float*)hbuf;
    u16* g1  = (u16*)hbuf;     // reused after LN consumes h
    u16* nf  = fb;             // reused after conv consumes fb

    hipMemsetAsync(grid_i, 0xFF, (size_t)GDIM*GDIM2*4, stream);
    hipMemsetAsync(fb + (size_t)NPTS*512, 0, 512*2, stream);

    scatter_kernel<<<NPTS/256, 256, 0, stream>>>(coords, grid_i);
    build_nbr<<<NPTS/256, 256, 0, stream>>>(coords, grid_i, nbr);
    cast_bf16<<<(NPTS*CCH/8)/256, 256, 0, stream>>>(feats, fb, NPTS*CCH/8);
    transpose_cast<<<dim3(16,16,27), dim3(32,8), 0, stream>>>(conv_w, wcT, 512, 512);
    transpose_cast<<<dim3(64,16,1),  dim3(32,8), 0, stream>>>(w1, w1T, 512, 2048);
    transpose_cast<<<dim3(16,64,1),  dim3(32,8), 0, stream>>>(w2, w2T, 2048, 512);

    conv_gemm<<<dim3(4,512), 256, 0, stream>>>(fb, nbr, wcT, conv_b, h);
    ln_kernel<<<NPTS/4, 256, 0, stream>>>(h, ln_g, ln_b, nf);

    for (int half = 0; half < 2; ++half) {
        mlp_gemm<1><<<dim3(8,512), 256, 0, stream>>>(
            nf, 512, w1T + (size_t)half*1024*512, 512, 512,
            b1 + half*1024, nullptr, nullptr, g1, 0);
        mlp_gemm<2><<<dim3(4,512), 256, 0, stream>>>(
            g1, 1024, w2T + half*1024, 2048, 1024,
            b2, feats, out, nullptr, half == 0);
    }
}

// Round 2
// 1302.003 us; speedup vs baseline: 1.2585x; 1.2585x over previous
//
#include <hip/hip_runtime.h>

typedef __attribute__((ext_vector_type(8))) short short8;
typedef __attribute__((ext_vector_type(4))) float f32x4;
typedef __attribute__((ext_vector_type(4))) float f4v;
typedef unsigned short u16;
typedef unsigned int u32;

#define NPTS 65536
#define CCH 512
#define GDIM 66
#define GDIM2 (66*66)

__device__ __forceinline__ u16 f2bf(float f) {
    u32 u = __builtin_bit_cast(u32, f);
    u32 r = (u + 0x7fffu + ((u >> 16) & 1u)) >> 16;
    return (u16)r;
}
__device__ __forceinline__ float bf2f(u16 h) {
    u32 u = ((u32)h) << 16;
    return __builtin_bit_cast(float, u);
}
__device__ __forceinline__ void gld16(const void* g, void* l) {
    __builtin_amdgcn_global_load_lds((const __attribute__((address_space(1))) void*)g,
                                     (__attribute__((address_space(3))) void*)l, 16, 0, 0);
}

// ---------------- setup kernels ----------------

__global__ void scatter_kernel(const int* __restrict__ coords, int* __restrict__ grid) {
    int i = blockIdx.x * 256 + threadIdx.x;
    if (i < NPTS) {
        int c0 = coords[3*i], c1 = coords[3*i+1], c2 = coords[3*i+2];
        grid[(c0+1)*GDIM2 + (c1+1)*GDIM + (c2+1)] = i;
    }
}

__global__ void build_nbr(const int* __restrict__ coords, const int* __restrict__ grid,
                          int* __restrict__ nbr) {
    int i = blockIdx.x * 256 + threadIdx.x;
    if (i >= NPTS) return;
    int c0 = coords[3*i], c1 = coords[3*i+1], c2 = coords[3*i+2];
    #pragma unroll
    for (int o = 0; o < 27; ++o) {
        int dx = o / 9, dy = (o / 3) % 3, dz = o % 3;
        int v = grid[(c0+dx)*GDIM2 + (c1+dy)*GDIM + (c2+dz)];
        nbr[o*NPTS + i] = (v < 0) ? NPTS : v;   // invalid -> zero row
    }
}

__global__ void cast_bf16(const float* __restrict__ in, u16* __restrict__ out, int n8) {
    int i = blockIdx.x * 256 + threadIdx.x;
    if (i >= n8) return;
    f4v a = *(const f4v*)(in + (size_t)i*8);
    f4v b = *(const f4v*)(in + (size_t)i*8 + 4);
    short8 o;
    #pragma unroll
    for (int j = 0; j < 4; ++j) { o[j] = (short)f2bf(a[j]); o[j+4] = (short)f2bf(b[j]); }
    *(short8*)(out + (size_t)i*8) = o;
}

// in: f32 [R][Cc] row-major, out: bf16 [Cc][R]
__global__ void transpose_cast(const float* __restrict__ in, u16* __restrict__ out,
                               int R, int Cc) {
    __shared__ float tile[32][33];
    size_t moff = (size_t)blockIdx.z * R * Cc;
    in += moff; out += moff;
    int tx = threadIdx.x, ty = threadIdx.y;
    #pragma unroll
    for (int j = 0; j < 4; ++j) {
        int r = blockIdx.y*32 + ty + j*8;
        int c = blockIdx.x*32 + tx;
        tile[ty + j*8][tx] = in[(size_t)r*Cc + c];
    }
    __syncthreads();
    #pragma unroll
    for (int j = 0; j < 4; ++j) {
        int orow = blockIdx.x*32 + ty + j*8;
        int ocol = blockIdx.y*32 + tx;
        out[(size_t)orow*R + ocol] = f2bf(tile[tx][ty + j*8]);
    }
}

// ---------------- 256x256-tile 8-wave double-buffered GEMM ----------------
// MODE 0: conv  — A gathered via nbr per offset (nT=216), out bf16 = acc+bias
// MODE 1: mlp1  — out bf16 = silu(acc+bias)
// MODE 2: mlp2  — out f32 = acc+bias+resid (first) or acc+out (accumulate)

template<int MODE>
__global__ __launch_bounds__(512, 2) void gemm256(
    const u16* __restrict__ A, int lda,
    const int* __restrict__ nbr,
    const u16* __restrict__ BT, int ldb,
    int nT,
    const float* __restrict__ bias,
    const float* __restrict__ resid,
    float* __restrict__ outf, u16* __restrict__ outb, int ldout, int first)
{
    __shared__ __align__(1024) char lds[131072];   // 2 bufs x (A 32KB + B 32KB)
    const int tid = threadIdx.x;
    const int w = tid >> 6, lane = tid & 63;
    const int wm = w >> 2, wn = w & 3;             // 2M x 4N waves, 128x64 out each
    const int row0 = blockIdx.y * 256, col0 = blockIdx.x * 256;
    const int srcChunk = (tid & 7) ^ ((tid >> 3) & 7);  // XOR-swizzled source chunk
    const int rowInTile = tid >> 3;                // 0..63 (row within 64-row round)

    f32x4 acc[8][4] = {};

    const u16* bptr[4];
    #pragma unroll
    for (int p = 0; p < 4; ++p)
        bptr[p] = BT + (size_t)(col0 + p*64 + rowInTile) * ldb + srcChunk*8;

    const u16* aptr[4];
    int idxC[4], idxN[4];
    if constexpr (MODE == 0) {
        #pragma unroll
        for (int p = 0; p < 4; ++p)
            idxC[p] = nbr[row0 + p*64 + rowInTile];
    } else {
        #pragma unroll
        for (int p = 0; p < 4; ++p)
            aptr[p] = A + (size_t)(row0 + p*64 + rowInTile) * lda + srcChunk*8;
        (void)idxC; (void)idxN;
    }

    auto stage = [&](int buf, int t) {
        char* la = lds + buf*65536;
        char* lb = la + 32768;
        if constexpr (MODE == 0) {
            int k0 = (t & 7) * 64;
            const u16* ab = A + k0 + srcChunk*8;
            #pragma unroll
            for (int p = 0; p < 4; ++p)
                gld16(ab + (size_t)idxC[p]*512, la + p*8192 + tid*16);
            size_t bo = (size_t)(t >> 3) * 262144 + k0;
            #pragma unroll
            for (int p = 0; p < 4; ++p)
                gld16(bptr[p] + bo, lb + p*8192 + tid*16);
        } else {
            int k0 = t * 64;
            #pragma unroll
            for (int p = 0; p < 4; ++p)
                gld16(aptr[p] + k0, la + p*8192 + tid*16);
            #pragma unroll
            for (int p = 0; p < 4; ++p)
                gld16(bptr[p] + k0, lb + p*8192 + tid*16);
        }
    };

    auto compute = [&](int buf) {
        const char* la = lds + buf*65536;
        const char* lb = la + 32768;
        #pragma unroll
        for (int kk = 0; kk < 2; ++kk) {
            const int chx = (kk*4 + (lane >> 4)) ^ (lane & 7);
            short8 bfr[4];
            #pragma unroll
            for (int j = 0; j < 4; ++j) {
                int rowB = wn*64 + j*16 + (lane & 15);
                bfr[j] = *(const short8*)(void*)(lb + rowB*128 + chx*16);
            }
            #pragma unroll
            for (int f = 0; f < 8; ++f) {
                int rowA = wm*128 + f*16 + (lane & 15);
                short8 afr = *(const short8*)(void*)(la + rowA*128 + chx*16);
                #pragma unroll
                for (int j = 0; j < 4; ++j)
                    acc[f][j] = __builtin_amdgcn_mfma_f32_16x16x32_bf16(afr, bfr[j], acc[f][j], 0, 0, 0);
            }
        }
    };

    stage(0, 0);
    __syncthreads();
    int cur = 0;
    #pragma unroll 1
    for (int t = 0; t < nT; ++t) {
        int tn = t + 1;
        if (tn < nT) {
            if constexpr (MODE == 0) {
                if ((tn & 7) == 0) {           // offset boundary: switch to prefetched idx
                    #pragma unroll
                    for (int p = 0; p < 4; ++p) idxC[p] = idxN[p];
                }
            }
            stage(cur ^ 1, tn);
            if constexpr (MODE == 0) {
                if ((tn & 7) == 1 && (tn >> 3) + 1 < 27) {   // prefetch next offset's rows
                    int on = (tn >> 3) + 1;
                    #pragma unroll
                    for (int p = 0; p < 4; ++p)
                        idxN[p] = nbr[on*NPTS + row0 + p*64 + rowInTile];
                }
            }
        }
        compute(cur);
        __syncthreads();
        cur ^= 1;
    }

    #pragma unroll
    for (int f = 0; f < 8; ++f) {
        int r = row0 + wm*128 + f*16 + (lane >> 4)*4;
        #pragma unroll
        for (int j = 0; j < 4; ++j) {
            int c = col0 + wn*64 + j*16 + (lane & 15);
            float bv = bias[c];
            #pragma unroll
            for (int q = 0; q < 4; ++q) {
                float v = acc[f][j][q];
                if constexpr (MODE == 0) {
                    outb[(size_t)(r+q)*ldout + c] = f2bf(v + bv);
                } else if constexpr (MODE == 1) {
                    float val = v + bv;
                    float sg = 1.f / (1.f + __expf(-val));
                    outb[(size_t)(r+q)*ldout + c] = f2bf(val * sg);
                } else {
                    size_t ix = (size_t)(r+q)*512 + c;
                    outf[ix] = first ? (v + bv + resid[ix]) : (v + outf[ix]);
                }
            }
        }
    }
}

// ---------------- LayerNorm: h bf16 -> nf bf16 ----------------

__global__ __launch_bounds__(256) void ln_kernel(const u16* __restrict__ h,
    const float* __restrict__ g, const float* __restrict__ b, u16* __restrict__ nf)
{
    int w = threadIdx.x >> 6, lane = threadIdx.x & 63;
    int row = blockIdx.x*4 + w;
    short8 v = *(const short8*)(h + (size_t)row*512 + lane*8);
    float x[8];
    #pragma unroll
    for (int j = 0; j < 8; ++j) x[j] = bf2f((u16)v[j]);
    float s = 0.f, ss = 0.f;
    #pragma unroll
    for (int j = 0; j < 8; ++j) { s += x[j]; ss += x[j]*x[j]; }
    #pragma unroll
    for (int m = 1; m < 64; m <<= 1) { s += __shfl_xor(s, m); ss += __shfl_xor(ss, m); }
    float mu = s * (1.f/512.f);
    float var = ss * (1.f/512.f) - mu*mu;
    float inv = rsqrtf(var + 1e-6f);
    short8 o;
    #pragma unroll
    for (int j = 0; j < 8; ++j) {
        int c = lane*8 + j;
        o[j] = (short)f2bf((x[j] - mu) * inv * g[c] + b[c]);
    }
    *(short8*)(nf + (size_t)row*512 + lane*8) = o;
}

// ---------------- launch ----------------

extern "C" void kernel_launch(void* const* d_in, const int* in_sizes, int n_in,
                              void* d_out, int out_size, void* d_ws, size_t ws_size,
                              hipStream_t stream) {
    const float* feats  = (const float*)d_in[0];
    const int*   coords = (const int*)d_in[1];
    const float* conv_w = (const float*)d_in[2];
    const float* conv_b = (const float*)d_in[3];
    const float* ln_g   = (const float*)d_in[4];
    const float* ln_b   = (const float*)d_in[5];
    const float* w1     = (const float*)d_in[6];
    const float* b1     = (const float*)d_in[7];
    const float* w2     = (const float*)d_in[8];
    const float* b2     = (const float*)d_in[9];
    float* out = (float*)d_out;
    char* ws = (char*)d_ws;

    size_t off = 0;
    auto take = [&](size_t bytes) -> void* {
        void* p = ws + off;
        off += (bytes + 1023) & ~(size_t)1023;
        return p;
    };
    int* grid_i = (int*)take((size_t)GDIM*GDIM2*4);
    int* nbr    = (int*)take(27ull*NPTS*4);
    u16* wcT    = (u16*)take(27ull*512*512*2);
    u16* w1T    = (u16*)take(2048ull*512*2);
    u16* w2T    = (u16*)take(512ull*2048*2);
    u16* fb     = (u16*)take((NPTS+1ull)*512*2);
    void* hbuf  = take(134217728ull);
    u16* h   = (u16*)hbuf;     // conv out, bf16 (64 MiB)
    u16* g1  = (u16*)hbuf;     // reused after LN consumes h (128 MiB)
    u16* nf  = fb;             // reused after conv consumes fb

    hipMemsetAsync(grid_i, 0xFF, (size_t)GDIM*GDIM2*4, stream);
    hipMemsetAsync(fb + (size_t)NPTS*512, 0, 512*2, stream);

    scatter_kernel<<<NPTS/256, 256, 0, stream>>>(coords, grid_i);
    build_nbr<<<NPTS/256, 256, 0, stream>>>(coords, grid_i, nbr);
    cast_bf16<<<(NPTS*CCH/8)/256, 256, 0, stream>>>(feats, fb, NPTS*CCH/8);
    transpose_cast<<<dim3(16,16,27), dim3(32,8), 0, stream>>>(conv_w, wcT, 512, 512);
    transpose_cast<<<dim3(64,16,1),  dim3(32,8), 0, stream>>>(w1, w1T, 512, 2048);
    transpose_cast<<<dim3(16,64,1),  dim3(32,8), 0, stream>>>(w2, w2T, 2048, 512);

    // conv: nT = 27 offsets * 8 K-steps
    gemm256<0><<<dim3(2,256), 512, 0, stream>>>(
        fb, 512, nbr, wcT, 512, 216, conv_b, nullptr, nullptr, h, 512, 0);

    ln_kernel<<<NPTS/4, 256, 0, stream>>>(h, ln_g, ln_b, nf);

    for (int half = 0; half < 2; ++half) {
        gemm256<1><<<dim3(4,256), 512, 0, stream>>>(
            nf, 512, nullptr, w1T + (size_t)half*1024*512, 512, 8,
            b1 + half*1024, nullptr, nullptr, g1, 1024, 0);
        gemm256<2><<<dim3(2,256), 512, 0, stream>>>(
            g1, 1024, nullptr, w2T + half*1024, 2048, 16,
            b2, feats, out, nullptr, 512, half == 0);
    }
}